// Round 4
// baseline (325.823 us; speedup 1.0000x reference)
//
#include <hip/hip_runtime.h>
#include <hip/hip_bf16.h>
#include <stdint.h>

#define BZv 4
#define QL 512
#define CL 1536
#define KVL 2048
#define EMB 1024
#define NH 16
#define HD 64
#define QSCALE 0.18033688011112042f  /* 0.125 * log2(e) */

typedef __attribute__((ext_vector_type(8))) short short8;
typedef __attribute__((ext_vector_type(4))) float floatx4;

__device__ __forceinline__ unsigned short f2b(float f) {
  union { float f; unsigned int u; } v; v.f = f;
  return (unsigned short)((v.u + 0x7FFFu + ((v.u >> 16) & 1u)) >> 16);
}

__device__ __forceinline__ ushort2 pk2(float a, float b) {
  union { __hip_bfloat162 h; ushort2 u; } c;
  c.h = __float22bfloat162_rn(make_float2(a, b));
  return c.u;
}

#if __has_builtin(__builtin_amdgcn_exp2f)
#define EXP2F(x) __builtin_amdgcn_exp2f(x)
#else
#define EXP2F(x) exp2f(x)
#endif

__device__ __forceinline__ void gload_lds16(const void* g, void* l) {
  __builtin_amdgcn_global_load_lds(
      (const __attribute__((address_space(1))) unsigned char*)g,
      (__attribute__((address_space(3))) unsigned char*)l, 16, 0, 0);
}

// ---------------- prep: fp32->bf16 + cache copies + w = exp(mask) ----------------
__global__ __launch_bounds__(256) void prep_kernel(
    const float* __restrict__ hid, const float* __restrict__ Wq, const float* __restrict__ Wk,
    const float* __restrict__ Wv, const float* __restrict__ Wo,
    const float* __restrict__ kc, const float* __restrict__ vc, const float* __restrict__ msk,
    unsigned short* __restrict__ Xb, unsigned short* __restrict__ Wqb, unsigned short* __restrict__ Wkb,
    unsigned short* __restrict__ Wvb, unsigned short* __restrict__ Wob,
    unsigned short* __restrict__ Kb, unsigned short* __restrict__ Vb,
    float* __restrict__ kf, float* __restrict__ vf, unsigned short* __restrict__ wb)
{
  const long HID4 = (long)BZv * QL * EMB / 4;
  const long W4   = (long)EMB * EMB / 4;
  const long C4   = (long)BZv * CL * EMB / 4;
  const long t0 = HID4, t1 = t0 + W4, t2 = t1 + W4, t3 = t2 + W4, t4 = t3 + W4;
  const long t5 = t4 + C4, t6 = t5 + C4;
  const long total = t6 + (long)BZv * KVL / 4;
  for (long i = (long)blockIdx.x * blockDim.x + threadIdx.x; i < total;
       i += (long)gridDim.x * blockDim.x) {
    if (i < t4) {
      const float* src; unsigned short* dst; long j;
      if (i < t0)      { src = hid; dst = Xb;  j = i; }
      else if (i < t1) { src = Wq;  dst = Wqb; j = i - t0; }
      else if (i < t2) { src = Wk;  dst = Wkb; j = i - t1; }
      else if (i < t3) { src = Wv;  dst = Wvb; j = i - t2; }
      else             { src = Wo;  dst = Wob; j = i - t3; }
      float4 v = ((const float4*)src)[j];
      ushort4 o; o.x = f2b(v.x); o.y = f2b(v.y); o.z = f2b(v.z); o.w = f2b(v.w);
      ((ushort4*)dst)[j] = o;
    } else if (i < t6) {
      bool isV = (i >= t5);
      long j = i - (isV ? t5 : t4);
      const float* src = isV ? vc : kc;
      float4 v = ((const float4*)src)[j];
      long e4 = j * 4;
      int b = (int)(e4 / ((long)CL * EMB));
      long rem = e4 - (long)b * CL * EMB;
      long doff = (long)b * KVL * EMB + rem;
      if (isV) {
        *((float4*)(vf + doff)) = v;
        int row = (int)(rem >> 10);                 // EMB = 1024
        float w = __expf(msk[b * KVL + row]);
        ushort4 o; o.x = f2b(v.x * w); o.y = f2b(v.y * w);
        o.z = f2b(v.z * w); o.w = f2b(v.w * w);
        *((ushort4*)(Vb + doff)) = o;
      } else {
        *((float4*)(kf + doff)) = v;
        ushort4 o; o.x = f2b(v.x); o.y = f2b(v.y); o.z = f2b(v.z); o.w = f2b(v.w);
        *((ushort4*)(Kb + doff)) = o;
      }
    } else {
      long j = i - t6;
      float4 m4 = ((const float4*)msk)[j];
      ushort4 o;
      o.x = f2b(__expf(m4.x)); o.y = f2b(__expf(m4.y));
      o.z = f2b(__expf(m4.z)); o.w = f2b(__expf(m4.w));
      ((ushort4*)wb)[j] = o;
    }
  }
}

// ---------------- fused QKV GEMM: 128x128 tiles, grid (24,16) ----------------
__global__ __launch_bounds__(256) void qkv_gemm(
    const unsigned short* __restrict__ Xb,
    const unsigned short* __restrict__ Wqb, const unsigned short* __restrict__ Wkb,
    const unsigned short* __restrict__ Wvb,
    const float* __restrict__ bq, const float* __restrict__ bk, const float* __restrict__ bv,
    const float* __restrict__ msk,
    unsigned short* __restrict__ Qb, unsigned short* __restrict__ Kb, unsigned short* __restrict__ Vb,
    float* __restrict__ kf, float* __restrict__ vf)
{
  __shared__ unsigned short At[128 * 32];
  __shared__ unsigned short Bt[128 * 32];
  const int tid = threadIdx.x, lane = tid & 63, wave = tid >> 6;
  const int quad = lane >> 4, l = lane & 15;
  const int mat = blockIdx.x >> 3;
  const int ncol = (blockIdx.x & 7) * 128;
  const int mbase = blockIdx.y * 128;
  const unsigned short* W = (mat == 0) ? Wqb : (mat == 1) ? Wkb : Wvb;
  const float* bias = (mat == 0) ? bq : (mat == 1) ? bk : bv;
  const int srow = tid >> 2, slds = tid & 3;
  const int rh = (wave & 1) * 64, ch = (wave >> 1) * 64;

  floatx4 zero = {0.f, 0.f, 0.f, 0.f};
  floatx4 acc[4][4];
#pragma unroll
  for (int i = 0; i < 4; i++)
#pragma unroll
    for (int j = 0; j < 4; j++) acc[i][j] = zero;

  for (int k0 = 0; k0 < EMB; k0 += 32) {
    __syncthreads();
#pragma unroll
    for (int s = 0; s < 2; s++) {
      int row = s * 64 + srow;
      int gc = slds ^ (row & 3);
      gload_lds16(Xb + (size_t)(mbase + row) * EMB + k0 + gc * 8, &At[row * 32 + slds * 8]);
    }
#pragma unroll
    for (int s = 0; s < 2; s++) {
      int row = s * 64 + srow;
      int gc = slds ^ (row & 3);
      gload_lds16(W + (size_t)(ncol + row) * EMB + k0 + gc * 8, &Bt[row * 32 + slds * 8]);
    }
    __syncthreads();
    short8 af[4], bfr[4];
#pragma unroll
    for (int rt = 0; rt < 4; rt++) {
      int row = rh + rt * 16 + l;
      af[rt] = *(const short8*)&At[row * 32 + ((quad ^ (row & 3)) * 8)];
    }
#pragma unroll
    for (int ct = 0; ct < 4; ct++) {
      int row = ch + ct * 16 + l;
      bfr[ct] = *(const short8*)&Bt[row * 32 + ((quad ^ (row & 3)) * 8)];
    }
#pragma unroll
    for (int rt = 0; rt < 4; rt++)
#pragma unroll
      for (int ct = 0; ct < 4; ct++)
        acc[rt][ct] = __builtin_amdgcn_mfma_f32_16x16x32_bf16(af[rt], bfr[ct], acc[rt][ct], 0, 0, 0);
  }

#pragma unroll
  for (int rt = 0; rt < 4; rt++)
#pragma unroll
    for (int r = 0; r < 4; r++) {
      int m = mbase + rh + rt * 16 + quad * 4 + r;
      size_t orow; float w = 1.f;
      if (mat == 0) orow = (size_t)m;
      else {
        orow = (size_t)(m >> 9) * KVL + CL + (m & 511);
        if (mat == 2) w = __expf(msk[orow]);
      }
#pragma unroll
      for (int ct = 0; ct < 4; ct++) {
        int col = ncol + ch + ct * 16 + l;
        float val = acc[rt][ct][r] + bias[col];
        if (mat == 0) {
          Qb[(size_t)m * EMB + col] = f2b(val * QSCALE);
        } else {
          size_t a = orow * EMB + col;
          if (mat == 1) { Kb[a] = f2b(val); kf[a] = val; }
          else          { Vb[a] = f2b(val * w); vf[a] = val; }
        }
      }
    }
}

// ---------------- V transpose: Vb[b][kv][h*64+d] -> Vtg[bh][d][kv], row 64 = w ----
__global__ __launch_bounds__(256) void vtrans_kernel(
    const unsigned short* __restrict__ Vb, const unsigned short* __restrict__ wb,
    unsigned short* __restrict__ Vtg)
{
  __shared__ unsigned short T[64 * 72];
  const int id = blockIdx.x;
  const int bh = id & 63, kt = id >> 6;
  const int b = bh >> 4, h = bh & 15;
  const int kv0 = kt * 64;
  const int tid = threadIdx.x;
  {
    const int r = tid >> 2, dbase = (tid & 3) * 16;
    const unsigned short* src = Vb + (size_t)(b * KVL + kv0 + r) * EMB + h * HD + dbase;
    uint4 lo = *(const uint4*)src;
    uint4 hi = *(const uint4*)(src + 8);
    *(uint4*)&T[r * 72 + dbase] = lo;
    *(uint4*)&T[r * 72 + dbase + 8] = hi;
  }
  __syncthreads();
  {
    const int d = tid >> 2, kcv = (tid & 3) * 16;
    unsigned short tmp[16];
#pragma unroll
    for (int j = 0; j < 16; j++) tmp[j] = T[(kcv + j) * 72 + d];
    unsigned short* dst = Vtg + ((size_t)bh * 65 + d) * KVL + kv0 + kcv;
    *(uint4*)dst = *(const uint4*)&tmp[0];
    *(uint4*)(dst + 8) = *(const uint4*)&tmp[8];
  }
  if (tid < 16) {
    ushort4 wv = *(const ushort4*)(wb + (size_t)b * KVL + kv0 + tid * 4);
    *(ushort4*)(Vtg + ((size_t)bh * 65 + 64) * KVL + kv0 + tid * 4) = wv;
  }
}

// ---------------- O-proj GEMM: 64x128 tiles, grid (8,32) ----------------
__global__ __launch_bounds__(256) void oproj_gemm(
    const unsigned short* __restrict__ A, const unsigned short* __restrict__ W,
    const float* __restrict__ bias, float* __restrict__ out)
{
  __shared__ unsigned short At[64 * 32];
  __shared__ unsigned short Bt[128 * 32];
  const int tid = threadIdx.x, lane = tid & 63, wave = tid >> 6;
  const int quad = lane >> 4, l = lane & 15;
  const int ncol = blockIdx.x * 128;
  const int mbase = blockIdx.y * 64;
  const int srow = tid >> 2, slds = tid & 3;
  const int rh = (wave & 1) * 32, ch = (wave >> 1) * 64;

  floatx4 zero = {0.f, 0.f, 0.f, 0.f};
  floatx4 acc[2][4];
#pragma unroll
  for (int i = 0; i < 2; i++)
#pragma unroll
    for (int j = 0; j < 4; j++) acc[i][j] = zero;

  for (int k0 = 0; k0 < EMB; k0 += 32) {
    __syncthreads();
    {
      int gc = slds ^ (srow & 3);
      gload_lds16(A + (size_t)(mbase + srow) * EMB + k0 + gc * 8, &At[srow * 32 + slds * 8]);
    }
#pragma unroll
    for (int s = 0; s < 2; s++) {
      int row = s * 64 + srow;
      int gc = slds ^ (row & 3);
      gload_lds16(W + (size_t)(ncol + row) * EMB + k0 + gc * 8, &Bt[row * 32 + slds * 8]);
    }
    __syncthreads();
    short8 af[2], bfr[4];
#pragma unroll
    for (int rt = 0; rt < 2; rt++) {
      int row = rh + rt * 16 + l;
      af[rt] = *(const short8*)&At[row * 32 + ((quad ^ (row & 3)) * 8)];
    }
#pragma unroll
    for (int ct = 0; ct < 4; ct++) {
      int row = ch + ct * 16 + l;
      bfr[ct] = *(const short8*)&Bt[row * 32 + ((quad ^ (row & 3)) * 8)];
    }
#pragma unroll
    for (int rt = 0; rt < 2; rt++)
#pragma unroll
      for (int ct = 0; ct < 4; ct++)
        acc[rt][ct] = __builtin_amdgcn_mfma_f32_16x16x32_bf16(af[rt], bfr[ct], acc[rt][ct], 0, 0, 0);
  }

#pragma unroll
  for (int ct = 0; ct < 4; ct++) {
    int col = ncol + ch + ct * 16 + l;
    float bb = bias[col];
#pragma unroll
    for (int rt = 0; rt < 2; rt++)
#pragma unroll
      for (int r = 0; r < 4; r++) {
        int m = mbase + rh + rt * 16 + quad * 4 + r;
        out[(size_t)m * EMB + col] = acc[rt][ct][r] + bb;
      }
  }
}

// ---------------- flash attention v4: split-kv in block, global V^T, no loop barrier
// grid 2048: id = qt*64 + bh; block q-tile 16; wave w takes kv tiles t = w, w+4, ...
__global__ __launch_bounds__(256) void attn_kernel(
    const unsigned short* __restrict__ Qb, const unsigned short* __restrict__ Kb,
    const unsigned short* __restrict__ Vtg, unsigned short* __restrict__ Cb)
{
  __shared__ unsigned short Pl[4][16 * 72];
  __shared__ float cmb[4][16][68];            // per wave, per q: O[64], m, den
  const int id = blockIdx.x;
  const int bh = id & 63, qt = id >> 6;       // qt 0..31
  const int b = bh >> 4, h = bh & 15;
  const int tid = threadIdx.x, lane = tid & 63, wave = tid >> 6;
  const int quad = lane >> 4, l = lane & 15;
  const int q0 = qt * 16;

  const unsigned short* qp = Qb + (size_t)(b * QL + q0 + l) * EMB + h * HD + quad * 8;
  const short8 bq0 = *(const short8*)qp;      // B-frag [n=q][k=d]
  const short8 bq1 = *(const short8*)(qp + 32);

  const unsigned short* kbase = Kb + (size_t)(b * KVL) * EMB + h * HD + quad * 8;
  const unsigned short* vtb = Vtg + (size_t)bh * 65 * KVL;

  floatx4 zero = {0.f, 0.f, 0.f, 0.f};
  floatx4 o[4], o4 = zero;
#pragma unroll
  for (int c = 0; c < 4; c++) o[c] = zero;
  float mr = -INFINITY;

  const int kv_end = CL + q0 + 16;
  const int ntiles = (kv_end + 63) >> 6;

  for (int t = wave; t < ntiles; t += 4) {
    const int kv0 = t * 64;
    short8 kc0[4], kc1[4], av0[4], av1[4];
#pragma unroll
    for (int c = 0; c < 4; c++) {
      const unsigned short* kp = kbase + (size_t)(kv0 + c * 16 + l) * EMB;
      kc0[c] = *(const short8*)kp;            // A-frag [m=kv][k=d]
      kc1[c] = *(const short8*)(kp + 32);
      const unsigned short* vpr = vtb + (size_t)(c * 16 + l) * KVL + kv0 + quad * 8;
      av0[c] = *(const short8*)vpr;           // A-frag [m=d][k=kv]
      av1[c] = *(const short8*)(vpr + 32);
    }
    const unsigned short* wpr = vtb + (size_t)64 * KVL + kv0 + quad * 8;
    const short8 vw0 = *(const short8*)wpr;   // broadcast A-frag: rows = w[kv]
    const short8 vw1 = *(const short8*)(wpr + 32);

    // S^T = K . Q^T : lane holds S^T[kv = c*16+quad*4+r][q = l]
    floatx4 s[4];
#pragma unroll
    for (int c = 0; c < 4; c++) {
      s[c] = __builtin_amdgcn_mfma_f32_16x16x32_bf16(kc0[c], bq0, zero, 0, 0, 0);
      s[c] = __builtin_amdgcn_mfma_f32_16x16x32_bf16(kc1[c], bq1, s[c], 0, 0, 0);
    }
    if (kv0 + 63 >= kv_end) {                 // frontier tile: causal mask
      const int lim = CL + q0 + l;
#pragma unroll
      for (int c = 0; c < 4; c++) {
        int kvb = kv0 + c * 16 + quad * 4;
#pragma unroll
        for (int r = 0; r < 4; r++)
          s[c][r] = (kvb + r <= lim) ? s[c][r] : -INFINITY;
      }
    }
    float t0 = fmaxf(fmaxf(s[0][0], s[0][1]), fmaxf(s[0][2], s[0][3]));
    float t1 = fmaxf(fmaxf(s[1][0], s[1][1]), fmaxf(s[1][2], s[1][3]));
    float t2 = fmaxf(fmaxf(s[2][0], s[2][1]), fmaxf(s[2][2], s[2][3]));
    float t3 = fmaxf(fmaxf(s[3][0], s[3][1]), fmaxf(s[3][2], s[3][3]));
    float lmax = fmaxf(fmaxf(t0, t1), fmaxf(t2, t3));
    lmax = fmaxf(lmax, __shfl_xor(lmax, 16, 64));
    lmax = fmaxf(lmax, __shfl_xor(lmax, 32, 64));
    float mnew = fmaxf(mr, lmax);
    float alpha = EXP2F(mr - mnew);
    mr = mnew;
#pragma unroll
    for (int c = 0; c < 4; c++) {
      float p0 = EXP2F(s[c][0] - mnew), p1 = EXP2F(s[c][1] - mnew);
      float p2 = EXP2F(s[c][2] - mnew), p3 = EXP2F(s[c][3] - mnew);
      ushort2 lo = pk2(p0, p1), hi = pk2(p2, p3);
      ushort4 pk; pk.x = lo.x; pk.y = lo.y; pk.z = hi.x; pk.w = hi.y;
      *(ushort4*)&Pl[wave][l * 72 + c * 16 + quad * 4] = pk;
    }
#pragma unroll
    for (int c = 0; c < 4; c++)
#pragma unroll
      for (int r = 0; r < 4; r++) o[c][r] *= alpha;
#pragma unroll
    for (int r = 0; r < 4; r++) o4[r] *= alpha;
    asm volatile("s_waitcnt lgkmcnt(0)" ::: "memory");
    short8 pf0 = *(const short8*)&Pl[wave][l * 72 + quad * 8];        // B-frag [n=q][k=kv]
    short8 pf1 = *(const short8*)&Pl[wave][l * 72 + 32 + quad * 8];
    o4 = __builtin_amdgcn_mfma_f32_16x16x32_bf16(vw0, pf0, o4, 0, 0, 0);
    o4 = __builtin_amdgcn_mfma_f32_16x16x32_bf16(vw1, pf1, o4, 0, 0, 0);
#pragma unroll
    for (int c = 0; c < 4; c++) {
      o[c] = __builtin_amdgcn_mfma_f32_16x16x32_bf16(av0[c], pf0, o[c], 0, 0, 0);
      o[c] = __builtin_amdgcn_mfma_f32_16x16x32_bf16(av1[c], pf1, o[c], 0, 0, 0);
    }
  }

  // write per-wave partials: lane (l,quad) holds O^T[d=c*16+quad*4+r][q=l]
#pragma unroll
  for (int c = 0; c < 4; c++)
    *(float4*)&cmb[wave][l][c * 16 + quad * 4] = *(float4*)&o[c];
  if (quad == 0) { cmb[wave][l][64] = mr; cmb[wave][l][65] = o4[0]; }
  __syncthreads();

  // combine: thread -> (q = tid>>4, d = (tid&15)*4 .. +3)
  {
    const int q = tid >> 4, dc = (tid & 15) * 4;
    float m0 = cmb[0][q][64], m1 = cmb[1][q][64], m2 = cmb[2][q][64], m3 = cmb[3][q][64];
    float mstar = fmaxf(fmaxf(m0, m1), fmaxf(m2, m3));
    float s0 = EXP2F(m0 - mstar), s1 = EXP2F(m1 - mstar);
    float s2 = EXP2F(m2 - mstar), s3 = EXP2F(m3 - mstar);
    float den = s0 * cmb[0][q][65] + s1 * cmb[1][q][65] +
                s2 * cmb[2][q][65] + s3 * cmb[3][q][65];
    float4 a0 = *(float4*)&cmb[0][q][dc];
    float4 a1 = *(float4*)&cmb[1][q][dc];
    float4 a2 = *(float4*)&cmb[2][q][dc];
    float4 a3 = *(float4*)&cmb[3][q][dc];
    float inv = 1.0f / den;
    float r0 = (s0 * a0.x + s1 * a1.x + s2 * a2.x + s3 * a3.x) * inv;
    float r1 = (s0 * a0.y + s1 * a1.y + s2 * a2.y + s3 * a3.y) * inv;
    float r2 = (s0 * a0.z + s1 * a1.z + s2 * a2.z + s3 * a3.z) * inv;
    float r3 = (s0 * a0.w + s1 * a1.w + s2 * a2.w + s3 * a3.w) * inv;
    ushort4 outv; outv.x = f2b(r0); outv.y = f2b(r1); outv.z = f2b(r2); outv.w = f2b(r3);
    *(ushort4*)(Cb + (size_t)(b * QL + q0 + q) * EMB + h * HD + dc) = outv;
  }
}

extern "C" void kernel_launch(void* const* d_in, const int* in_sizes, int n_in,
                              void* d_out, int out_size, void* d_ws, size_t ws_size,
                              hipStream_t stream) {
  const float* hid  = (const float*)d_in[0];
  const float* mask = (const float*)d_in[1];
  const float* kc   = (const float*)d_in[2];
  const float* vc   = (const float*)d_in[3];
  const float* Wq   = (const float*)d_in[4];
  const float* bq   = (const float*)d_in[5];
  const float* Wk   = (const float*)d_in[6];
  const float* bk   = (const float*)d_in[7];
  const float* Wv   = (const float*)d_in[8];
  const float* bv   = (const float*)d_in[9];
  const float* Wo   = (const float*)d_in[10];
  const float* bo   = (const float*)d_in[11];

  float* out_f = (float*)d_out;
  float* kf = out_f + (size_t)BZv * QL * EMB;
  float* vf = kf + (size_t)BZv * KVL * EMB;

  char* p = (char*)d_ws;
  unsigned short* Xb  = (unsigned short*)p; p += (size_t)BZv * QL * EMB * 2;
  unsigned short* Wqb = (unsigned short*)p; p += (size_t)EMB * EMB * 2;
  unsigned short* Wkb = (unsigned short*)p; p += (size_t)EMB * EMB * 2;
  unsigned short* Wvb = (unsigned short*)p; p += (size_t)EMB * EMB * 2;
  unsigned short* Wob = (unsigned short*)p; p += (size_t)EMB * EMB * 2;
  unsigned short* Qb  = (unsigned short*)p; p += (size_t)BZv * QL * EMB * 2;
  unsigned short* Kb  = (unsigned short*)p; p += (size_t)BZv * KVL * EMB * 2;
  unsigned short* Vb  = (unsigned short*)p; p += (size_t)BZv * KVL * EMB * 2;
  unsigned short* Cb  = (unsigned short*)p; p += (size_t)BZv * QL * EMB * 2;
  unsigned short* wbp = (unsigned short*)p; p += (size_t)BZv * KVL * 2;
  unsigned short* Vtg = (unsigned short*)p; p += (size_t)NH * BZv * 65 * KVL * 2;

  prep_kernel<<<2048, 256, 0, stream>>>(hid, Wq, Wk, Wv, Wo, kc, vc, mask,
                                        Xb, Wqb, Wkb, Wvb, Wob, Kb, Vb, kf, vf, wbp);
  qkv_gemm<<<dim3(24, 16), 256, 0, stream>>>(Xb, Wqb, Wkb, Wvb, bq, bk, bv, mask,
                                             Qb, Kb, Vb, kf, vf);
  vtrans_kernel<<<2048, 256, 0, stream>>>(Vb, wbp, Vtg);
  attn_kernel<<<2048, 256, 0, stream>>>(Qb, Kb, Vtg, Cb);
  oproj_gemm<<<dim3(8, 32), 256, 0, stream>>>(Cb, Wob, bo, out_f);
}